// Round 5
// baseline (111.239 us; speedup 1.0000x reference)
//
#include <hip/hip_runtime.h>
#include <math.h>

#define BNS 0.99999500003749972f   // 1/sqrt(1+1e-5)

__device__ __forceinline__ float eluf(float v) {
    return v > 0.f ? v : (__expf(v) - 1.f);
}
__device__ __forceinline__ float sigmf(float u) {
    return 1.f / (1.f + __expf(-u));
}
// swizzle: +1 word every 32 to break power-of-2 stride bank conflicts
__device__ __forceinline__ int zpw(int i) { return i + (i >> 5); }

#define PROW 1032    // pre row stride (zpw(999)=1030)
#define ZROW 1120    // zbuf row stride (max zpw index 1119 for K=63 lane63 overread)
#define PADZ 32      // left/right zero pad (>= 31 = max K/2)

// ---------------- fused kernel A: stem + spatial reduce + branch pipeline ----------------
// grid 768: b = bid/3, g = bid%3. block 320 = 5 waves.
// Phase 1 (tid<250): stem conv2d(2x3) + BN + ELU + spatial reduce -> preL[5][1000] in LDS.
// Phase 2: wave w handles channel w: BN1+ELU+SimAM -> temporal conv K -> BN2+ELU+SimAM -> pool 40.

template<int K>
__device__ __forceinline__ void branch_wave(
    const float* __restrict__ prow,   // LDS, zpw-indexed channel row
    float g1s, float b1v,
    const float* __restrict__ twp,    // K temporal weights (uniform)
    float g2s, float b2v,
    float* __restrict__ zrow,         // LDS scratch row, zpw-indexed
    float* __restrict__ out40)        // global
{
    const int lane = threadIdx.x & 63;
    const int tb = lane * 16;

    // zero pads: logical [0,32) and [1032,1064)
    if (lane < 32) { zrow[zpw(lane)] = 0.f; zrow[zpw(1032 + lane)] = 0.f; }

    // ---- BN1 + ELU, accumulate sums ----
    float y[16];
    float s1 = 0.f, s2 = 0.f;
#pragma unroll
    for (int j = 0; j < 16; ++j) {
        const int t = tb + j;
        float v = 0.f;
        if (t < 1000) v = eluf(prow[zpw(t)] * g1s + b1v);
        y[j] = v; s1 += v; s2 += v * v;
    }
#pragma unroll
    for (int m = 32; m > 0; m >>= 1) { s1 += __shfl_xor(s1, m, 64); s2 += __shfl_xor(s2, m, 64); }
    {
        const float mu = s1 * 1e-3f;
        const float var = s2 * 1e-3f - mu * mu;
        const float iv = 1.f / (2.f * var + 1e-12f);
#pragma unroll
        for (int j = 0; j < 16; ++j) {
            const int t = tb + j;
            if (t < 1000) {
                const float d = y[j] - mu;
                zrow[zpw(PADZ + t)] = sigmf(1.f / (d * d * iv + 1e-4f + 1e-12f)) * y[j];
            }
        }
    }
    // wave-synchronous LDS: same wave wrote, same wave reads; compiler inserts lgkmcnt waits.

    // ---- temporal depthwise conv ('same'), 16-wide register sliding window ----
    const int Lb = PADZ + tb - (K / 2);
    float win[16];
#pragma unroll
    for (int j = 0; j < 15; ++j) win[j] = zrow[zpw(Lb + j)];
    float a[16];
#pragma unroll
    for (int j = 0; j < 16; ++j) a[j] = 0.f;
#pragma unroll
    for (int d = 0; d < K; ++d) {
        win[15] = zrow[zpw(Lb + d + 15)];
        const float wv = twp[d];
#pragma unroll
        for (int j = 0; j < 16; ++j) a[j] += win[j] * wv;
#pragma unroll
        for (int j = 0; j < 15; ++j) win[j] = win[j + 1];
    }

    // ---- BN2 + ELU + SimAM ----
    float u[16];
    s1 = 0.f; s2 = 0.f;
#pragma unroll
    for (int j = 0; j < 16; ++j) {
        const int t = tb + j;
        float v = 0.f;
        if (t < 1000) v = eluf(a[j] * g2s + b2v);
        u[j] = v; s1 += v; s2 += v * v;
    }
#pragma unroll
    for (int m = 32; m > 0; m >>= 1) { s1 += __shfl_xor(s1, m, 64); s2 += __shfl_xor(s2, m, 64); }
    {
        const float mu = s1 * 1e-3f;
        const float var = s2 * 1e-3f - mu * mu;
        const float iv = 1.f / (2.f * var + 1e-12f);
#pragma unroll
        for (int j = 0; j < 16; ++j) {
            const int t = tb + j;
            if (t < 1000) {
                const float d = u[j] - mu;
                zrow[zpw(PADZ + t)] = sigmf(1.f / (d * d * iv + 1e-4f + 1e-12f)) * u[j];
            }
        }
    }

    // ---- adaptive pool 1000 -> 40 ----
    if (lane < 40) {
        float s = 0.f;
#pragma unroll
        for (int q = 0; q < 25; ++q) s += zrow[zpw(PADZ + lane * 25 + q)];
        out40[lane] = s * (1.f / 25.f);
    }
}

__global__ __launch_bounds__(320) void k_fused(
    const float* __restrict__ x,
    const float* __restrict__ stem_w,
    const float* __restrict__ stem_g, const float* __restrict__ stem_b,
    const float* __restrict__ sw1, const float* __restrict__ sw2, const float* __restrict__ sw3,
    const float* __restrict__ g1a, const float* __restrict__ b1a,
    const float* __restrict__ tw1,
    const float* __restrict__ g2a, const float* __restrict__ b2a,
    const float* __restrict__ g1b, const float* __restrict__ b1b,
    const float* __restrict__ tw2,
    const float* __restrict__ g2b, const float* __restrict__ b2b,
    const float* __restrict__ g1c, const float* __restrict__ b1c,
    const float* __restrict__ tw3,
    const float* __restrict__ g2c, const float* __restrict__ b2c,
    float* __restrict__ pooled)   // (256,15,40)
{
    __shared__ float preL[5 * PROW];   // 20.6 KB
    __shared__ float zsh[5 * ZROW];    // 22.4 KB

    const int tid = threadIdx.x;
    const int bid = blockIdx.x;
    const int b = bid / 3, g = bid % 3;
    const float* xb = x + b * 22000;

    // ---------- phase 1: stem ----------
    if (tid < 250) {
        const int t0 = tid * 4;
        const int mode = (tid == 0) ? 0 : (tid == 249 ? 2 : 1);
        const float* swp = (g == 0 ? sw1 : g == 1 ? sw2 : sw3);

        float wv[5][6], gs[5], bsv[5];
#pragma unroll
        for (int c = 0; c < 5; ++c) {
            const int C = g * 5 + c;
#pragma unroll
            for (int j = 0; j < 6; ++j) wv[c][j] = stem_w[C * 6 + j];
            gs[c] = stem_g[C] * BNS;
            bsv[c] = stem_b[C];
        }

        float acc[5][4];
#pragma unroll
        for (int c = 0; c < 5; ++c)
#pragma unroll
            for (int j = 0; j < 4; ++j) acc[c][j] = 0.f;

        float cw[6], nw[6];
        // row loader: window x[r][t0-1 .. t0+4] with zero W-pads
        #define LOADROW(r, w6)                                                        \
        {                                                                             \
            const float* rp = xb + (r) * 1000;                                        \
            if (mode == 1) {                                                          \
                const float4 v4 = *reinterpret_cast<const float4*>(rp + t0 - 1);      \
                const float2 v2 = *reinterpret_cast<const float2*>(rp + t0 + 3);      \
                w6[0] = v4.x; w6[1] = v4.y; w6[2] = v4.z; w6[3] = v4.w;               \
                w6[4] = v2.x; w6[5] = v2.y;                                           \
            } else if (mode == 0) {                                                   \
                const float4 v4 = *reinterpret_cast<const float4*>(rp);               \
                w6[0] = 0.f; w6[1] = v4.x; w6[2] = v4.y; w6[3] = v4.z;                \
                w6[4] = v4.w; w6[5] = rp[4];                                          \
            } else {                                                                  \
                const float4 v4 = *reinterpret_cast<const float4*>(rp + 995);         \
                w6[0] = v4.x; w6[1] = v4.y; w6[2] = v4.z; w6[3] = v4.w;               \
                w6[4] = rp[999]; w6[5] = 0.f;                                         \
            }                                                                         \
        }

        LOADROW(0, cw)
#pragma unroll
        for (int i = 0; i < 22; ++i) {
            if (i < 21) {
                LOADROW(i + 1, nw)
            } else {
#pragma unroll
                for (int j = 0; j < 6; ++j) nw[j] = 0.f;   // bottom H-pad row
            }
#pragma unroll
            for (int c = 0; c < 5; ++c) {
                const float sv = swp[c * 22 + i];
#pragma unroll
                for (int j = 0; j < 4; ++j) {
                    float v = wv[c][0] * cw[j] + wv[c][1] * cw[j + 1] + wv[c][2] * cw[j + 2]
                            + wv[c][3] * nw[j] + wv[c][4] * nw[j + 1] + wv[c][5] * nw[j + 2];
                    v = eluf(v * gs[c] + bsv[c]);
                    acc[c][j] += v * sv;
                }
            }
#pragma unroll
            for (int j = 0; j < 6; ++j) cw[j] = nw[j];
        }
        #undef LOADROW

#pragma unroll
        for (int c = 0; c < 5; ++c)
#pragma unroll
            for (int j = 0; j < 4; ++j)
                preL[c * PROW + zpw(t0 + j)] = acc[c][j];
    }
    __syncthreads();

    // ---------- phase 2: wave-per-channel branch ----------
    const int w = tid >> 6;          // channel within group, 0..4
    float* zrow = zsh + w * ZROW;
    const float* prow = preL + w * PROW;
    float* out40 = pooled + (b * 15 + g * 5 + w) * 40;

    if (g == 0) {
        branch_wave<15>(prow, g1a[w] * BNS, b1a[w], tw1 + w * 15, g2a[w] * BNS, b2a[w], zrow, out40);
    } else if (g == 1) {
        branch_wave<31>(prow, g1b[w] * BNS, b1b[w], tw2 + w * 31, g2b[w] * BNS, b2b[w], zrow, out40);
    } else {
        branch_wave<63>(prow, g1c[w] * BNS, b1c[w], tw3 + w * 63, g2c[w] * BNS, b2c[w], zrow, out40);
    }
}

// ---------------- kernel B: head (per batch), 128 threads ----------------
__global__ __launch_bounds__(128) void k_head(
    const float* __restrict__ pooled,   // (256,15,40)
    const float* __restrict__ pw_w, const float* __restrict__ pw_g, const float* __restrict__ pw_b,
    const float* __restrict__ d1_w, const float* __restrict__ d1_ow, const float* __restrict__ d1_ob,
    const float* __restrict__ d2_w, const float* __restrict__ d2_ow, const float* __restrict__ d2_ob,
    const float* __restrict__ fc_w, const float* __restrict__ fc_b,
    float* __restrict__ out)            // (256,4)
{
    __shared__ float P[600];
    __shared__ float A[200];
    __shared__ float Bv[200];
    __shared__ float C1[180];
    __shared__ float C2[135];
    __shared__ float D[125];
    __shared__ float mu5[5], iv5[5];

    const int b = blockIdx.x, tid = threadIdx.x;

    for (int i = tid; i < 600; i += 128) P[i] = pooled[b * 600 + i];
    __syncthreads();

    for (int i = tid; i < 200; i += 128) {
        int o = i / 40, t = i % 40;
        float s = 0.f;
        for (int cc = 0; cc < 15; ++cc) s += P[cc * 40 + t] * pw_w[o * 15 + cc];
        float v = s * (pw_g[o] * BNS) + pw_b[o];
        A[i] = eluf(v);
    }
    __syncthreads();

    if (tid < 5) {
        float s = 0.f;
        for (int t = 0; t < 40; ++t) s += A[tid * 40 + t];
        float mu = s * (1.f / 40.f);
        float v2 = 0.f;
        for (int t = 0; t < 40; ++t) { float d = A[tid * 40 + t] - mu; v2 += d * d; }
        mu5[tid] = mu;
        iv5[tid] = 1.f / (2.f * (v2 * (1.f / 40.f)) + 1e-12f);
    }
    __syncthreads();

    for (int i = tid; i < 200; i += 128) {
        int o = i / 40;
        float a = A[i];
        float d = a - mu5[o];
        float e = d * d * iv5[o] + 1e-4f;
        Bv[i] = sigmf(1.f / (e + 1e-12f)) * a;
    }
    __syncthreads();

    for (int i = tid; i < 180; i += 128) {
        int cc = i / 36, t = i % 36;
        float o = 0.f;
        for (int k = 0; k < 5; ++k) {
            float off = d1_ob[cc * 5 + k];
            for (int d = 0; d < 5; ++d) off += Bv[cc * 40 + t + d] * d1_ow[(cc * 5 + k) * 5 + d];
            float pos = (float)(t + k) + off;
            float fl = floorf(pos);
            float f = pos - fl;
            int i0 = (int)fl;
            float v0 = (i0 >= 0 && i0 < 40) ? Bv[cc * 40 + i0] : 0.f;
            float v1 = (i0 + 1 >= 0 && i0 + 1 < 40) ? Bv[cc * 40 + i0 + 1] : 0.f;
            o += (v0 * (1.f - f) + v1 * f) * d1_w[cc * 5 + k];
        }
        C1[i] = o;
    }
    __syncthreads();

    for (int i = tid; i < 135; i += 128) {
        int cc = i / 27, t = i % 27;
        float o = 0.f;
        for (int k = 0; k < 10; ++k) {
            float off = d2_ob[cc * 10 + k];
            for (int d = 0; d < 10; ++d) off += C1[cc * 36 + t + d] * d2_ow[(cc * 10 + k) * 10 + d];
            float pos = (float)(t + k) + off;
            float fl = floorf(pos);
            float f = pos - fl;
            int i0 = (int)fl;
            float v0 = (i0 >= 0 && i0 < 36) ? C1[cc * 36 + i0] : 0.f;
            float v1 = (i0 + 1 >= 0 && i0 + 1 < 36) ? C1[cc * 36 + i0 + 1] : 0.f;
            o += (v0 * (1.f - f) + v1 * f) * d2_w[cc * 10 + k];
        }
        C2[i] = o;
    }
    __syncthreads();

    for (int i = tid; i < 125; i += 128) {
        int cc = i / 25, j = i % 25;
        int s0 = (j * 27) / 25;
        int e0 = ((j + 1) * 27 + 24) / 25;
        float s = 0.f;
        for (int q = s0; q < e0; ++q) s += C2[cc * 27 + q];
        D[i] = s / (float)(e0 - s0);
    }
    __syncthreads();

    if (tid < 64) {
        float part0 = 0.f, part1 = 0.f, part2 = 0.f, part3 = 0.f;
        for (int i = tid; i < 125; i += 64) {
            const float dv = D[i];
            part0 += dv * fc_w[0 * 125 + i];
            part1 += dv * fc_w[1 * 125 + i];
            part2 += dv * fc_w[2 * 125 + i];
            part3 += dv * fc_w[3 * 125 + i];
        }
#pragma unroll
        for (int m = 32; m > 0; m >>= 1) {
            part0 += __shfl_xor(part0, m, 64);
            part1 += __shfl_xor(part1, m, 64);
            part2 += __shfl_xor(part2, m, 64);
            part3 += __shfl_xor(part3, m, 64);
        }
        if (tid == 0) {
            out[b * 4 + 0] = part0 + fc_b[0];
            out[b * 4 + 1] = part1 + fc_b[1];
            out[b * 4 + 2] = part2 + fc_b[2];
            out[b * 4 + 3] = part3 + fc_b[3];
        }
    }
}

extern "C" void kernel_launch(void* const* d_in, const int* in_sizes, int n_in,
                              void* d_out, int out_size, void* d_ws, size_t ws_size,
                              hipStream_t stream) {
    const float* x      = (const float*)d_in[0];
    const float* stem_w = (const float*)d_in[1];
    const float* stem_g = (const float*)d_in[2];
    const float* stem_b = (const float*)d_in[3];
    const float* b1_sw = (const float*)d_in[4];
    const float* b1_g1 = (const float*)d_in[5];
    const float* b1_b1 = (const float*)d_in[6];
    const float* b1_tw = (const float*)d_in[7];
    const float* b1_g2 = (const float*)d_in[8];
    const float* b1_b2 = (const float*)d_in[9];
    const float* b2_sw = (const float*)d_in[10];
    const float* b2_g1 = (const float*)d_in[11];
    const float* b2_b1 = (const float*)d_in[12];
    const float* b2_tw = (const float*)d_in[13];
    const float* b2_g2 = (const float*)d_in[14];
    const float* b2_b2 = (const float*)d_in[15];
    const float* b3_sw = (const float*)d_in[16];
    const float* b3_g1 = (const float*)d_in[17];
    const float* b3_b1 = (const float*)d_in[18];
    const float* b3_tw = (const float*)d_in[19];
    const float* b3_g2 = (const float*)d_in[20];
    const float* b3_b2 = (const float*)d_in[21];
    const float* pw_w  = (const float*)d_in[22];
    const float* pw_g  = (const float*)d_in[23];
    const float* pw_b  = (const float*)d_in[24];
    const float* d1_w  = (const float*)d_in[25];
    const float* d1_ow = (const float*)d_in[26];
    const float* d1_ob = (const float*)d_in[27];
    const float* d2_w  = (const float*)d_in[28];
    const float* d2_ow = (const float*)d_in[29];
    const float* d2_ob = (const float*)d_in[30];
    const float* fc_w  = (const float*)d_in[31];
    const float* fc_b  = (const float*)d_in[32];

    float* pooled = (float*)d_ws;   // 256*15*40 f32

    k_fused<<<768, 320, 0, stream>>>(
        x, stem_w, stem_g, stem_b, b1_sw, b2_sw, b3_sw,
        b1_g1, b1_b1, b1_tw, b1_g2, b1_b2,
        b2_g1, b2_b1, b2_tw, b2_g2, b2_b2,
        b3_g1, b3_b1, b3_tw, b3_g2, b3_b2,
        pooled);

    k_head<<<256, 128, 0, stream>>>(
        pooled, pw_w, pw_g, pw_b,
        d1_w, d1_ow, d1_ob, d2_w, d2_ow, d2_ob,
        fc_w, fc_b, (float*)d_out);
}